// Round 3
// baseline (1866.660 us; speedup 1.0000x reference)
//
#include <hip/hip_runtime.h>

typedef unsigned short u16;
typedef unsigned int   u32;
typedef signed char    i8;
typedef __attribute__((ext_vector_type(4))) int  i32x4;
typedef __attribute__((ext_vector_type(2))) long i64x2;

// ---------------- problem constants ----------------
#define NSTEP 512
#define NBG 4          // batch groups (16 rows each)
#define NCG 8          // column groups (64 h-cols each)

// ---------------- workspace layout (bytes) ----------------
#define OFF_QX8   0ull
#define SZ_QX8    (32768ull*512)            // x quantized, int8
#define OFF_QWT8  (OFF_QX8 + SZ_QX8)
#define SZ_QT8    (1536ull*512)             // W^T / R^T quantized, int8
#define OFF_QRT8  (OFF_QWT8 + SZ_QT8)
#define OFF_QWX   (OFF_QRT8 + SZ_QT8)
#define SZ_QWX    (32768ull*1536)           // Wx quantized, int8
#define OFF_QBX   (OFF_QWX + SZ_QWX)        // 1536 int
#define OFF_QBR   (OFF_QBX + 6144)          // 1536 int
#define OFF_LUT   (OFF_QBR + 6144)          // 256 int sigmoid + 256 int tanh
#define OFF_RING  (OFF_LUT + 2048)          // 2 slots x 4 bg x 16KB tagged h-words
#define RING_WORDS (2*4*4096)
#define SZ_RING   (RING_WORDS*4ull)
#define WS_NEED   (OFF_RING + SZ_RING)

// ---------------- helpers ----------------
__device__ __forceinline__ int iclip8(int v){ return v < -128 ? -128 : (v > 127 ? 127 : v); }

// round-half-even of (v / 2^k) for integer v (matches jnp.round on exact values)
__device__ __forceinline__ int rhe(int v, int k){
  int b = v >> k;                 // floor
  int r = v & ((1 << k) - 1);
  int half = 1 << (k - 1);
  return b + ((r > half) || (r == half && (b & 1)));
}

__device__ __forceinline__ int qi8(float x, float s){
  float q = rintf(x * s);
  q = fminf(fmaxf(q, -128.f), 127.f);
  return (int)q;
}

// MFMA i8 wrapper: tolerate either i32x4- or i64x2-typed builtin signature.
template<typename V>
__device__ __forceinline__ auto mfma_i8_try(V a, V b, i32x4 c, int)
  -> decltype(__builtin_amdgcn_mfma_i32_16x16x64_i8(a, b, c, 0, 0, 0)) {
  return __builtin_amdgcn_mfma_i32_16x16x64_i8(a, b, c, 0, 0, 0);
}
template<typename V>
__device__ __forceinline__ i32x4 mfma_i8_try(V a, V b, i32x4 c, long) {
  return __builtin_amdgcn_mfma_i32_16x16x64_i8(
      __builtin_bit_cast(i64x2, a), __builtin_bit_cast(i64x2, b), c, 0, 0, 0);
}
__device__ __forceinline__ i32x4 mfma_i8(i32x4 a, i32x4 b, i32x4 c){
  return mfma_i8_try(a, b, c, 0);
}

// coherent (LLC) 8-byte store of two tagged words — no fence needed
__device__ __forceinline__ void llc_store64(unsigned long long addr, u32 w0, u32 w1){
  unsigned long long d = (unsigned long long)w0 | ((unsigned long long)w1 << 32);
  asm volatile("global_store_dwordx2 %0, %1, off sc0 sc1" :: "v"(addr), "v"(d) : "memory");
}

// producer byte offset within an image for the dwordx2 covering local cols c0..c0+3
// image layout [m=8][g=4][row=16][j=8] u32 words; word(kp,row): kp=m*32+g*8+j
__device__ __forceinline__ int prod_off(int cg, int c0, int row){
  int gp = (c0 >> 4) & 3;
  int j  = (c0 >> 1) & 7;
  return cg*2048 + gp*512 + row*32 + j*4;
}

// ---------------- phase 0: quantization / tables ----------------
__global__ void k0a_qx(const float* __restrict__ x, u32* __restrict__ qx8, int n4){
  int i = blockIdx.x * blockDim.x + threadIdx.x;
  int st = gridDim.x * blockDim.x;
  for (; i < n4; i += st) {
    float4 v = ((const float4*)x)[i];
    u32 b0 = (u32)(qi8(v.x, 16.f) & 0xFF);
    u32 b1 = (u32)(qi8(v.y, 16.f) & 0xFF);
    u32 b2 = (u32)(qi8(v.z, 16.f) & 0xFF);
    u32 b3 = (u32)(qi8(v.w, 16.f) & 0xFF);
    qx8[i] = b0 | (b1 << 8) | (b2 << 16) | (b3 << 24);
  }
}

__global__ void k0b_qwr(const float* __restrict__ W, const float* __restrict__ Rm,
                        i8* __restrict__ qwT8, i8* __restrict__ qrT8){
  int idx = blockIdx.x * 256 + threadIdx.x;       // 0 .. 2*786432-1
  if (idx >= 2*786432) return;
  int m = idx >= 786432;
  int rem = idx - m * 786432;                     // = k*1536 + n (coalesced read)
  int k = rem / 1536;
  int n = rem - k * 1536;
  const float* s = m ? Rm : W;
  i8* d = m ? qrT8 : qwT8;
  d[n*512 + k] = (i8)qi8(s[rem], 1024.f);
}

__global__ void k0c_misc(const float* __restrict__ bx, const float* __restrict__ br,
                         int* __restrict__ qbx, int* __restrict__ qbr,
                         int* __restrict__ lut, u32* __restrict__ ring){
  int i = blockIdx.x * 256 + threadIdx.x;         // 4096 threads
  if (i < 1536) {
    qbx[i] = iclip8((int)rintf(bx[i] * 256.f));
    qbr[i] = iclip8((int)rintf(br[i] * 256.f));
  }
  if (i < 256) {
    double v = (i - 128) * 0.125;                 // all possible pre-activations
    float sg = (float)(1.0 / (1.0 + exp(-v)));
    int qs = (int)rintf(sg * 256.f);
    lut[i] = qs < 0 ? 0 : (qs > 255 ? 255 : qs);
    float th = (float)tanh(v);
    lut[256 + i] = iclip8((int)rintf(th * 128.f));
  }
  // zero the ring EVERY launch: tags are >=1, so no garbage/leftover can match
#pragma unroll
  for (int r = 0; r < RING_WORDS/4096; r++)
    ring[r*4096 + i] = 0u;
}

// ---------------- phase 1: Wx = fq(xq @ Wq, 4), stored int8 ----------------
// 128x128 tile, BK=64, int8 MFMA; 4 waves each a 64x64 quadrant of 4x4 tiles.
__global__ __launch_bounds__(256) void k1_gemm_wx(const i8* __restrict__ qx8,
                                                  const i8* __restrict__ qwT8,
                                                  i8* __restrict__ qwx){
  __shared__ i8 xs[128][80];
  __shared__ i8 ws[128][80];
  int bid = blockIdx.x;
  int n0 = (bid % 12) * 128;
  int m0 = (bid / 12) * 128;
  int tid = threadIdx.x;
  int lane = tid & 63, wid = tid >> 6;
  int wm = wid >> 1, wn = wid & 1;
  int g = lane >> 4, l15 = lane & 15;

  i32x4 acc[4][4] = {};
  for (int kc = 0; kc < 512; kc += 64) {
    __syncthreads();
#pragma unroll
    for (int p = 0; p < 4; p++) {
      int idx = p*256 + tid;           // 1024 x 16B chunks (512 per matrix)
      int mat = idx >> 9;
      int i2  = idx & 511;
      int r   = i2 >> 2;
      int c16 = (i2 & 3) << 4;
      const i8* src = mat ? qwT8 : qx8;
      int base = mat ? n0 : m0;
      uint4 val = *(const uint4*)&src[(size_t)(base + r)*512 + kc + c16];
      if (mat) *(uint4*)&ws[r][c16] = val;
      else     *(uint4*)&xs[r][c16] = val;
    }
    __syncthreads();
    i32x4 a[4], b[4];
#pragma unroll
    for (int t = 0; t < 4; t++) {
      a[t] = *(const i32x4*)&xs[wm*64 + t*16 + l15][g*16];
      b[t] = *(const i32x4*)&ws[wn*64 + t*16 + l15][g*16];
    }
#pragma unroll
    for (int i = 0; i < 4; i++)
#pragma unroll
      for (int j = 0; j < 4; j++)
        acc[i][j] = mfma_i8(a[i], b[j], acc[i][j]);
  }
  // epilogue: fq to int8: q = rhe(acc/1024)  (exact integers)
#pragma unroll
  for (int i = 0; i < 4; i++)
#pragma unroll
    for (int j = 0; j < 4; j++)
#pragma unroll
      for (int r = 0; r < 4; r++) {
        int q = iclip8(rhe(acc[i][j][r], 10));
        int row = m0 + wm*64 + i*16 + g*4 + r;   // C/D: row = 4*(lane>>4)+reg
        int col = n0 + wn*64 + j*16 + l15;       //      col = lane&15
        qwx[(size_t)row * 1536 + col] = (i8)q;
      }
}

// ---------------- phase 2: 512-step recurrence ----------------
// 32 WGs: bg owns 16 batch rows, cg owns 64 h-cols (192 Rh cols). N-split:
// each wave owns 3 output tiles x full K=512 (R as int8 B-frags in registers,
// 96 VGPR). No cross-wave reduce; ONE barrier per step. h exchanged via
// LLC-coherent tagged words (int8 pairs + 16-bit step tag), fence-free.
__global__ __launch_bounds__(256, 1) void k2_gru(const float* __restrict__ h0,
                                                 const i8*  __restrict__ qwx,
                                                 const i8*  __restrict__ qrT8,
                                                 const int* __restrict__ qbx,
                                                 const int* __restrict__ qbr,
                                                 const int* __restrict__ lut,
                                                 u32* __restrict__ ring,
                                                 float* __restrict__ out){
  const int bid = blockIdx.x;
  const int bg  = bid & 3;
  const int cg  = bid >> 2;                       // 0..7
  const int tid = threadIdx.x;
  const int lane = tid & 63, wid = tid >> 6;
  const int g = lane >> 4, l15 = lane & 15;

  __shared__ int rhb[2*16*196];                   // [slot][row][196(pad)] quantized Rh+br
  __shared__ int l_sig[256], l_th[256];

  if (tid < 256) { l_sig[tid] = lut[tid]; l_th[tid] = lut[256 + tid]; }

  // ---- R fragments (B operand), int8, resident: 3 n-tiles x 8 k-chunks
  i32x4 rf[3][8];
  int qbrv[3];
#pragma unroll
  for (int nt = 0; nt < 3; nt++) {
    int T = wid*3 + nt;                           // tile 0..11
    int colR = (T >> 2)*512 + cg*64 + (T & 3)*16 + l15;
    qbrv[nt] = qbr[colR];
#pragma unroll
    for (int m = 0; m < 8; m++)
      rf[nt][m] = *(const i32x4*)&qrT8[(size_t)colR*512 + m*64 + g*16];
  }

  // ---- own h state: 4 elements per thread (row = tid>>4, cols c0..c0+3)
  const int row = tid >> 4;
  const int c0  = (tid & 15) << 2;
  int bxz[4], bxr[4], bxn[4];
#pragma unroll
  for (int b = 0; b < 4; b++) {
    int col = cg*64 + c0 + b;
    bxz[b] = qbx[col]; bxr[b] = qbx[512 + col]; bxn[b] = qbx[1024 + col];
  }
  int qh[4];
  {
    float4 h4 = *(const float4*)&h0[(size_t)(bg*16 + row)*512 + cg*64 + c0];
    qh[0] = qi8(h4.x, 128.f); qh[1] = qi8(h4.y, 128.f);
    qh[2] = qi8(h4.z, 128.f); qh[3] = qi8(h4.w, 128.f);
  }
  const unsigned long long ringb = (unsigned long long)ring;
  // publish h(0): slot 0, tag 1
  {
    u32 w0 = (u32)(qh[0] & 0xFF) | ((u32)(qh[1] & 0xFF) << 8) | (1u << 16);
    u32 w1 = (u32)(qh[2] & 0xFF) | ((u32)(qh[3] & 0xFF) << 8) | (1u << 16);
    llc_store64(ringb + (unsigned long long)(bg*16384 + prod_off(cg, c0, row)), w0, w1);
  }

  // consumer poll base: lane reads rows l15, k-group g, all m (byte g*512+l15*32)
  const unsigned long long lanebase = (unsigned long long)(g*512 + l15*32);

  for (int t = 0; t < NSTEP; t++) {
    // prefetch Wx for this step (plain cached loads; independent of h)
    const i8* wxp = qwx + (size_t)t*98304 + (size_t)(bg*16 + row)*1536 + cg*64;
    int wzw = *(const int*)(wxp + c0);
    int wrw = *(const int*)(wxp + 512 + c0);
    int wgw = *(const int*)(wxp + 1024 + c0);

    // ---- poll the 64 tagged words this lane needs (h(t), slot t&1, tag t+1)
    const u32 want  = (u32)(t + 1);
    const u32 want2 = want | (want << 16);
    unsigned long long a0 = ringb +
        (unsigned long long)(((t & 1)*4 + bg)*16384) + lanebase;
    unsigned long long a1 = a0 + 4096, a2 = a0 + 8192, a3 = a0 + 12288;
    uint4 p0,p1,p2,p3,p4,p5,p6,p7,p8,p9,p10,p11,p12,p13,p14,p15;
    int spins = 0;
    for (;;) {
      asm volatile(
        "global_load_dwordx4 %0,  %16, off sc0 sc1\n\t"
        "global_load_dwordx4 %1,  %16, off offset:16 sc0 sc1\n\t"
        "global_load_dwordx4 %2,  %16, off offset:2048 sc0 sc1\n\t"
        "global_load_dwordx4 %3,  %16, off offset:2064 sc0 sc1\n\t"
        "global_load_dwordx4 %4,  %17, off sc0 sc1\n\t"
        "global_load_dwordx4 %5,  %17, off offset:16 sc0 sc1\n\t"
        "global_load_dwordx4 %6,  %17, off offset:2048 sc0 sc1\n\t"
        "global_load_dwordx4 %7,  %17, off offset:2064 sc0 sc1\n\t"
        "global_load_dwordx4 %8,  %18, off sc0 sc1\n\t"
        "global_load_dwordx4 %9,  %18, off offset:16 sc0 sc1\n\t"
        "global_load_dwordx4 %10, %18, off offset:2048 sc0 sc1\n\t"
        "global_load_dwordx4 %11, %18, off offset:2064 sc0 sc1\n\t"
        "global_load_dwordx4 %12, %19, off sc0 sc1\n\t"
        "global_load_dwordx4 %13, %19, off offset:16 sc0 sc1\n\t"
        "global_load_dwordx4 %14, %19, off offset:2048 sc0 sc1\n\t"
        "global_load_dwordx4 %15, %19, off offset:2064 sc0 sc1\n\t"
        "s_waitcnt vmcnt(0)"
        : "=&v"(p0), "=&v"(p1), "=&v"(p2), "=&v"(p3),
          "=&v"(p4), "=&v"(p5), "=&v"(p6), "=&v"(p7),
          "=&v"(p8), "=&v"(p9), "=&v"(p10), "=&v"(p11),
          "=&v"(p12), "=&v"(p13), "=&v"(p14), "=&v"(p15)
        : "v"(a0), "v"(a1), "v"(a2), "v"(a3)
        : "memory");
      u32 diff = 0u;
#define TCHK(P) \
      diff |= __builtin_amdgcn_perm((P).y, (P).x, 0x07060302u) ^ want2; \
      diff |= __builtin_amdgcn_perm((P).w, (P).z, 0x07060302u) ^ want2;
      TCHK(p0) TCHK(p1) TCHK(p2) TCHK(p3) TCHK(p4) TCHK(p5) TCHK(p6) TCHK(p7)
      TCHK(p8) TCHK(p9) TCHK(p10) TCHK(p11) TCHK(p12) TCHK(p13) TCHK(p14) TCHK(p15)
#undef TCHK
      if (diff == 0u) break;
      if (++spins > (1 << 25)) break;   // safety valve
      __builtin_amdgcn_s_sleep(1);
    }

    // ---- pack A dwords (strip tags) and run the 24 MFMAs
    uint4 P[16] = {p0,p1,p2,p3,p4,p5,p6,p7,p8,p9,p10,p11,p12,p13,p14,p15};
    i32x4 acc[3] = {};
#pragma unroll
    for (int m = 0; m < 8; m++) {
      uint4 u = P[2*m], v = P[2*m + 1];
      i32x4 a;
      a.x = (int)__builtin_amdgcn_perm(u.y, u.x, 0x05040100u);
      a.y = (int)__builtin_amdgcn_perm(u.w, u.z, 0x05040100u);
      a.z = (int)__builtin_amdgcn_perm(v.y, v.x, 0x05040100u);
      a.w = (int)__builtin_amdgcn_perm(v.w, v.z, 0x05040100u);
      acc[0] = mfma_i8(a, rf[0][m], acc[0]);
      acc[1] = mfma_i8(a, rf[1][m], acc[1]);
      acc[2] = mfma_i8(a, rf[2][m], acc[2]);
    }

    // ---- quantize Rh, add br, write rhb (int8-domain, exact)
    int* rhbs = &rhb[(t & 1)*3136];
#pragma unroll
    for (int nt = 0; nt < 3; nt++) {
      int col = (wid*3 + nt)*16 + l15;            // 0..191
#pragma unroll
      for (int r = 0; r < 4; r++) {
        int q1 = iclip8(rhe(acc[nt][r], 13));     // fq(h@R, 4)
        rhbs[(4*g + r)*196 + col] = iclip8(rhe(q1*16 + qbrv[nt], 4)); // fq(Rh+br,4)
      }
    }
    __syncthreads();                              // the ONLY barrier per step

    // ---- gates + state update for this thread's 4 elements
    const int* rb = &rhb[(t & 1)*3136 + row*196];
    i32x4 rz4 = *(const i32x4*)&rb[c0];
    i32x4 rr4 = *(const i32x4*)&rb[64 + c0];
    i32x4 rg4 = *(const i32x4*)&rb[128 + c0];
#pragma unroll
    for (int b = 0; b < 4; b++) {
      int wz = (int)(i8)(wzw >> (8*b));
      int wr = (int)(i8)(wrw >> (8*b));
      int wg = (int)(i8)(wgw >> (8*b));
      int uz = l_sig[128 + iclip8(rhe(16*(wz + rz4[b]) + bxz[b], 5))];
      int ur = l_sig[128 + iclip8(rhe(16*(wr + rr4[b]) + bxr[b], 5))];
      int qrh = iclip8(rhe(ur * rg4[b], 8));
      int qg  = l_th[128 + iclip8(rhe(16*(wg + qrh) + bxn[b], 5))];
      int qold = iclip8(rhe(uz * qh[b], 8));
      int qnew = iclip8(rhe((256 - uz) * qg, 8));
      qh[b] = iclip8(qold + qnew);
    }

    // ---- publish h(t+1) FIRST (earliest cross-WG visibility), then out
    {
      u32 tg = (u32)(t + 2) << 16;
      u32 w0 = (u32)(qh[0] & 0xFF) | ((u32)(qh[1] & 0xFF) << 8) | tg;
      u32 w1 = (u32)(qh[2] & 0xFF) | ((u32)(qh[3] & 0xFF) << 8) | tg;
      llc_store64(ringb + (unsigned long long)((((t + 1) & 1)*4 + bg)*16384 +
                                               prod_off(cg, c0, row)), w0, w1);
    }
    float4 ov;
    ov.x = qh[0] * 0.0078125f; ov.y = qh[1] * 0.0078125f;
    ov.z = qh[2] * 0.0078125f; ov.w = qh[3] * 0.0078125f;
    *(float4*)&out[((size_t)t*64 + bg*16 + row)*512 + cg*64 + c0] = ov;
  }
}

// ---------------- launch ----------------
extern "C" void kernel_launch(void* const* d_in, const int* in_sizes, int n_in,
                              void* d_out, int out_size, void* d_ws, size_t ws_size,
                              hipStream_t stream) {
  const float* x  = (const float*)d_in[0];
  const float* h0 = (const float*)d_in[1];
  const float* W  = (const float*)d_in[2];
  const float* R  = (const float*)d_in[3];
  const float* bx = (const float*)d_in[4];
  const float* br = (const float*)d_in[5];
  float* out = (float*)d_out;

  if (ws_size < WS_NEED) return;   // insufficient scratch; fail loudly

  char* ws = (char*)d_ws;
  i8*  qx8   = (i8*) (ws + OFF_QX8);
  i8*  qwT8  = (i8*) (ws + OFF_QWT8);
  i8*  qrT8  = (i8*) (ws + OFF_QRT8);
  i8*  qwx   = (i8*) (ws + OFF_QWX);
  int* qbx   = (int*)(ws + OFF_QBX);
  int* qbr   = (int*)(ws + OFF_QBR);
  int* lut   = (int*)(ws + OFF_LUT);
  u32* ring  = (u32*)(ws + OFF_RING);

  k0a_qx  <<<2048, 256, 0, stream>>>(x, (u32*)qx8, 32768*512/4);
  k0b_qwr <<<6144, 256, 0, stream>>>(W, R, qwT8, qrT8);
  k0c_misc<<<16,   256, 0, stream>>>(bx, br, qbx, qbr, lut, ring);
  k1_gemm_wx<<<3072, 256, 0, stream>>>(qx8, qwT8, qwx);
  k2_gru  <<<32, 256, 0, stream>>>(h0, qwx, qrT8, qbx, qbr, lut, ring, out);
}